// Round 6
// baseline (424.412 us; speedup 1.0000x reference)
//
#include <hip/hip_runtime.h>
#include <math.h>

#define NCLASS 40
#define BEDG 1024

typedef float f32x4 __attribute__((ext_vector_type(4)));
typedef __bf16 bf16x8 __attribute__((ext_vector_type(8)));

typedef __attribute__((address_space(1))) const void gv_t;
typedef __attribute__((address_space(3))) void lv_t;
#define GLOAD_LDS16(g, l) __builtin_amdgcn_global_load_lds((gv_t*)(g), (lv_t*)(l), 16, 0, 0)
#define NTL(p) __builtin_nontemporal_load(p)

__device__ inline unsigned short f2bf(float f) {
  unsigned u = __float_as_uint(f);
  unsigned r = (u + 0x7fff + ((u >> 16) & 1)) >> 16;
  return (unsigned short)r;
}
__device__ inline float bflo(unsigned v) { return __uint_as_float(v << 16); }
__device__ inline float bfhi(unsigned v) { return __uint_as_float(v & 0xffff0000u); }
__device__ inline float bf2f(unsigned short v) { return __uint_as_float((unsigned)v << 16); }

// ---------------- CSR build: deterministic bucket-by-XCD ----------------
__global__ void k_bcount(const int* __restrict__ dst, int E, int PART,
                         int* __restrict__ bcnt) {
  __shared__ int lc[8];
  int k = blockIdx.x;
  if (threadIdx.x < 8) lc[threadIdx.x] = 0;
  __syncthreads();
  int lo = k * BEDG, hi = min(lo + BEDG, E);
  for (int i = lo + threadIdx.x; i < hi; i += blockDim.x)
    atomicAdd(&lc[NTL(&dst[i]) / PART], 1);
  __syncthreads();
  if (threadIdx.x < 8) bcnt[k * 8 + threadIdx.x] = lc[threadIdx.x];
}

// one block per bucket: exclusive scan of its column of bcnt
__global__ void k_bscanA(int* __restrict__ bcnt, int nbB, int* __restrict__ btot) {
  __shared__ int tmp[256];
  __shared__ int carryS;
  int b = blockIdx.x;
  int tid = threadIdx.x;
  if (tid == 0) carryS = 0;
  __syncthreads();
  for (int c0 = 0; c0 < nbB; c0 += 256) {
    int idx = c0 + tid;
    int v = (idx < nbB) ? bcnt[idx * 8 + b] : 0;
    tmp[tid] = v;
    __syncthreads();
    for (int d = 1; d < 256; d <<= 1) {
      int t = (tid >= d) ? tmp[tid - d] : 0;
      __syncthreads();
      tmp[tid] += t;
      __syncthreads();
    }
    if (idx < nbB) bcnt[idx * 8 + b] = carryS + tmp[tid] - v;
    __syncthreads();
    if (tid == 255) carryS += tmp[255];
    __syncthreads();
  }
  if (tid == 0) btot[b] = carryS;
}

__global__ void k_bbase(const int* __restrict__ btot, int* __restrict__ bbase) {
  if (threadIdx.x == 0) {
    int s = 0;
    for (int b = 0; b < 8; ++b) {
      bbase[b] = s;
      s += btot[b];
    }
    bbase[8] = s;
  }
}

// place packed (dstLocal<<17 | src) records, bucket-contiguous.
__global__ void k_place(const int* __restrict__ dst, const int* __restrict__ src, int E,
                        int PART, const int* __restrict__ bcnt,
                        const int* __restrict__ bbase, int* __restrict__ ebuf) {
  __shared__ int lbase[8];
  __shared__ int lcnt[8];
  int k = blockIdx.x;
  if (threadIdx.x < 8) {
    lbase[threadIdx.x] = bbase[threadIdx.x] + bcnt[k * 8 + threadIdx.x];
    lcnt[threadIdx.x] = 0;
  }
  __syncthreads();
  int lo = k * BEDG, hi = min(lo + BEDG, E);
  for (int i = lo + threadIdx.x; i < hi; i += blockDim.x) {
    int d = NTL(&dst[i]);
    int s = NTL(&src[i]);
    int p = d / PART;
    int r = atomicAdd(&lcnt[p], 1);
    ebuf[lbase[p] + r] = (int)(((unsigned)(d - p * PART) << 17) | (unsigned)s);
  }
}

// per-XCD histogram from its own bucket (nt reads; atomics stay L2-local).
__global__ void k_hist2(const int* __restrict__ ebuf, const int* __restrict__ bbase,
                        int PART, int* __restrict__ cnt) {
  int p = blockIdx.x & 7;
  int lo = bbase[p], hi = bbase[p + 1];
  int base0 = p * PART;
  int i = lo + (blockIdx.x >> 3) * blockDim.x + threadIdx.x;
  int stride = (gridDim.x >> 3) * blockDim.x;
  for (; i < hi; i += stride)
    atomicAdd(&cnt[base0 + (((unsigned)NTL(&ebuf[i])) >> 17)], 1);
}

// per-XCD CSR fill (nt ebuf reads keep col window resident in L2).
__global__ void k_fill2(const int* __restrict__ ebuf, const int* __restrict__ bbase,
                        int PART, int* __restrict__ cursor, int* __restrict__ col) {
  int p = blockIdx.x & 7;
  int lo = bbase[p], hi = bbase[p + 1];
  int base0 = p * PART;
  int i = lo + (blockIdx.x >> 3) * blockDim.x + threadIdx.x;
  int stride = (gridDim.x >> 3) * blockDim.x;
  for (; i < hi; i += stride) {
    unsigned pk = (unsigned)NTL(&ebuf[i]);
    int pos = atomicAdd(&cursor[base0 + (pk >> 17)], 1);
    col[pos] = (int)(pk & 0x1FFFFu);
  }
}

__global__ void k_scan1(const int* __restrict__ cnt, int* __restrict__ off,
                        int* __restrict__ bsum, int n) {
  __shared__ int tmp[256];
  int tid = threadIdx.x;
  int base = blockIdx.x * 1024 + tid * 4;
  int v0 = 0, v1 = 0, v2 = 0, v3 = 0;
  if (base + 0 < n) v0 = cnt[base + 0];
  if (base + 1 < n) v1 = cnt[base + 1];
  if (base + 2 < n) v2 = cnt[base + 2];
  if (base + 3 < n) v3 = cnt[base + 3];
  int s = v0 + v1 + v2 + v3;
  tmp[tid] = s;
  __syncthreads();
  for (int d = 1; d < 256; d <<= 1) {
    int t = (tid >= d) ? tmp[tid - d] : 0;
    __syncthreads();
    tmp[tid] += t;
    __syncthreads();
  }
  int excl = tmp[tid] - s;
  if (base + 0 < n) off[base + 0] = excl;
  excl += v0;
  if (base + 1 < n) off[base + 1] = excl;
  excl += v1;
  if (base + 2 < n) off[base + 2] = excl;
  excl += v2;
  if (base + 3 < n) off[base + 3] = excl;
  if (tid == 255) bsum[blockIdx.x] = tmp[255];
}

__global__ void k_scan2(const int* __restrict__ bsum, int* __restrict__ boff, int nb) {
  __shared__ int tmp[128];
  int tid = threadIdx.x;
  int v = (tid < nb) ? bsum[tid] : 0;
  tmp[tid] = v;
  __syncthreads();
  for (int d = 1; d < 128; d <<= 1) {
    int t = (tid >= d) ? tmp[tid - d] : 0;
    __syncthreads();
    tmp[tid] += t;
    __syncthreads();
  }
  boff[tid] = tmp[tid] - v;
}

__global__ void k_scan3(int* __restrict__ off, const int* __restrict__ boff,
                        int* __restrict__ cursor, int n, int E) {
  int i = blockIdx.x * blockDim.x + threadIdx.x;
  if (i < n) {
    int o = off[i] + boff[i >> 10];
    off[i] = o;
    cursor[i] = o;
  }
  if (i == 0) off[n] = E;
}

// ---------------- casts / weight prep ----------------
__global__ void k_cast(const float4* __restrict__ x, uint4* __restrict__ xb, int n8) {
  int i = blockIdx.x * blockDim.x + threadIdx.x;
  if (i >= n8) return;
  float4 a = x[i * 2], b = x[i * 2 + 1];
  uint4 o;
  o.x = (unsigned)f2bf(a.x) | ((unsigned)f2bf(a.y) << 16);
  o.y = (unsigned)f2bf(a.z) | ((unsigned)f2bf(a.w) << 16);
  o.z = (unsigned)f2bf(b.x) | ((unsigned)f2bf(b.y) << 16);
  o.w = (unsigned)f2bf(b.z) | ((unsigned)f2bf(b.w) << 16);
  xb[i] = o;
}

// Wth layout: [half][COLS][128] bf16. half0=Wl^T, half1=Wr^T.
__global__ void k_prepw(const float* __restrict__ W1l, const float* __restrict__ W1r,
                        const float* __restrict__ W2l, const float* __restrict__ W2r,
                        const float* __restrict__ W3l, const float* __restrict__ W3r,
                        unsigned short* __restrict__ Wth1, unsigned short* __restrict__ Wth2,
                        unsigned short* __restrict__ Wth3) {
  int idx = blockIdx.x * blockDim.x + threadIdx.x;
  if (idx < 32768) {
    int h = idx >> 14, c = (idx >> 7) & 127, k = idx & 127;
    const float* W = h ? W1r : W1l;
    Wth1[idx] = f2bf(W[k * 128 + c]);
  } else if (idx < 65536) {
    int j = idx - 32768;
    int h = j >> 14, c = (j >> 7) & 127, k = j & 127;
    const float* W = h ? W2r : W2l;
    Wth2[j] = f2bf(W[k * 128 + c]);
  } else if (idx < 65536 + 16384) {
    int j = idx - 65536;
    int h = j >> 13, c = (j >> 7) & 63, k = j & 127;
    float v = 0.f;
    if (c < NCLASS) v = (h ? W3r : W3l)[k * NCLASS + c];
    Wth3[j] = f2bf(v);
  }
}

// ---------------- mean aggregation, width 128, uint4 gathers ----------------
#define ACC8(u, sc)                          \
  acc[0] = fmaf(bflo(u.x), sc, acc[0]);      \
  acc[1] = fmaf(bfhi(u.x), sc, acc[1]);      \
  acc[2] = fmaf(bflo(u.y), sc, acc[2]);      \
  acc[3] = fmaf(bfhi(u.y), sc, acc[3]);      \
  acc[4] = fmaf(bflo(u.z), sc, acc[4]);      \
  acc[5] = fmaf(bfhi(u.z), sc, acc[5]);      \
  acc[6] = fmaf(bflo(u.w), sc, acc[6]);      \
  acc[7] = fmaf(bfhi(u.w), sc, acc[7]);

__global__ void k_aggb(const char* __restrict__ X, const int* __restrict__ off,
                       const int* __restrict__ col, int n, uint4* __restrict__ out) {
  int wid = (blockIdx.x * blockDim.x + threadIdx.x) >> 6;
  int lane = threadIdx.x & 63;
  if (wid >= n) return;
  int g = lane >> 4, q = lane & 15;
  unsigned qb = (unsigned)q << 4;
  int s = off[wid], e = off[wid + 1];
  float acc[8];
#pragma unroll
  for (int t = 0; t < 8; ++t) acc[t] = 0.f;
  int e1 = e - 1;
  for (int j = s; j < e; j += 8) {
    int i0 = j + g, i1 = i0 + 4;
    int c0 = NTL(&col[min(i0, e1)]);
    int c1 = NTL(&col[min(i1, e1)]);
    float s0 = (i0 < e) ? 1.f : 0.f;
    float s1 = (i1 < e) ? 1.f : 0.f;
    uint4 u0 = *(const uint4*)(X + (((unsigned)c0 << 8) + qb));
    uint4 u1 = *(const uint4*)(X + (((unsigned)c1 << 8) + qb));
    ACC8(u0, s0);
    ACC8(u1, s1);
  }
#pragma unroll
  for (int t = 0; t < 8; ++t) {
    acc[t] += __shfl_xor(acc[t], 16);
    acc[t] += __shfl_xor(acc[t], 32);
  }
  float inv = 1.0f / fmaxf((float)(e - s), 1.0f);
  uint4 o;
  o.x = (unsigned)f2bf(acc[0] * inv) | ((unsigned)f2bf(acc[1] * inv) << 16);
  o.y = (unsigned)f2bf(acc[2] * inv) | ((unsigned)f2bf(acc[3] * inv) << 16);
  o.z = (unsigned)f2bf(acc[4] * inv) | ((unsigned)f2bf(acc[5] * inv) << 16);
  o.w = (unsigned)f2bf(acc[6] * inv) | ((unsigned)f2bf(acc[7] * inv) << 16);
  if (lane < 16) out[(size_t)wid * 16 + lane] = o;
}

// ---------------- MFMA GEMM ----------------
template <int COLS, int HALVES, int EPI>
__global__ __launch_bounds__(256) void k_gemm_mfma(
    const unsigned short* __restrict__ Aagg, const unsigned short* __restrict__ Aroot,
    const unsigned short* __restrict__ Wth, const float* __restrict__ bias, int n,
    float* __restrict__ outF, unsigned short* __restrict__ outB) {
  constexpr int RF = 4;
  constexpr int CF = 4;
  __shared__ unsigned short aS[128 * 128];
  __shared__ unsigned short wS[COLS * 128];
  int tid = threadIdx.x;
  int w = tid >> 6, lane = tid & 63, l15 = lane & 15, kg = lane >> 4;
  int rowBase = blockIdx.x * 128;
  int r0 = (w >> 1) * 64;
  int c0 = (w & 1) * 64;

  f32x4 acc[RF][CF];
#pragma unroll
  for (int i = 0; i < RF; ++i)
#pragma unroll
    for (int j = 0; j < CF; ++j) acc[i][j] = (f32x4){0.f, 0.f, 0.f, 0.f};

#pragma unroll
  for (int half = 0; half < HALVES; ++half) {
    if (half) __syncthreads();
    {
      const unsigned short* As = half ? Aroot : Aagg;
#pragma unroll
      for (int it = 0; it < 8; ++it) {
        int row = it * 16 + (tid >> 4);
        int g = rowBase + row;
        g = (g < n) ? g : (n - 1);
        int cb = (tid & 15) << 4;
        int sb = cb ^ ((row & 7) << 4);
        const char* src = (const char*)(As + (size_t)g * 128) + sb;
        char* dst = (char*)aS + it * 4096 + (tid >> 6) * 1024;
        GLOAD_LDS16(src, dst);
      }
      const unsigned short* Ws = Wth + (size_t)half * COLS * 128;
#pragma unroll
      for (int it = 0; it < COLS / 16; ++it) {
        int c = it * 16 + (tid >> 4);
        int cb = (tid & 15) << 4;
        int sb = cb ^ ((c & 7) << 4);
        const char* src = (const char*)(Ws + (size_t)c * 128) + sb;
        char* dst = (char*)wS + it * 4096 + (tid >> 6) * 1024;
        GLOAD_LDS16(src, dst);
      }
      asm volatile("s_waitcnt vmcnt(0)" ::: "memory");
      __syncthreads();
    }
#pragma unroll
    for (int ks = 0; ks < 4; ++ks) {
      int kb = ks * 64 + kg * 16;
      bf16x8 av[RF], bv[CF];
#pragma unroll
      for (int i = 0; i < RF; ++i) {
        int row = r0 + i * 16 + l15;
        av[i] = *(const bf16x8*)((const char*)aS + row * 256 + (kb ^ ((row & 7) << 4)));
      }
#pragma unroll
      for (int j = 0; j < CF; ++j) {
        int c = c0 + j * 16 + l15;
        bv[j] = *(const bf16x8*)((const char*)wS + c * 256 + (kb ^ ((c & 7) << 4)));
      }
#pragma unroll
      for (int i = 0; i < RF; ++i)
#pragma unroll
        for (int j = 0; j < CF; ++j)
          acc[i][j] = __builtin_amdgcn_mfma_f32_16x16x32_bf16(av[i], bv[j], acc[i][j], 0, 0, 0);
    }
  }

  if (EPI == 3) {
    bool leftHalf = (c0 == 0);
    unsigned short* R3b = (unsigned short*)outF;
    float bcol[CF];
#pragma unroll
    for (int j = 0; j < CF; ++j) {
      int c = c0 + j * 16 + l15;
      bcol[j] = (!leftHalf && (c - 64) < NCLASS) ? bias[c - 64] : 0.f;
    }
#pragma unroll
    for (int i = 0; i < RF; ++i) {
#pragma unroll
      for (int r = 0; r < 4; ++r) {
        int row = rowBase + r0 + i * 16 + kg * 4 + r;
        if (row >= n) continue;
#pragma unroll
        for (int j = 0; j < CF; ++j) {
          int c = c0 + j * 16 + l15;
          if (leftHalf) {
            outB[(size_t)row * 64 + c] = f2bf(acc[i][j][r]);
          } else {
            R3b[(size_t)row * 64 + (c - 64)] = f2bf(acc[i][j][r] + bcol[j]);
          }
        }
      }
    }
  } else {
    float bcol[CF];
#pragma unroll
    for (int j = 0; j < CF; ++j) bcol[j] = bias[c0 + j * 16 + l15];
#pragma unroll
    for (int i = 0; i < RF; ++i) {
#pragma unroll
      for (int r = 0; r < 4; ++r) {
        int row = rowBase + r0 + i * 16 + kg * 4 + r;
        if (row >= n) continue;
#pragma unroll
        for (int j = 0; j < CF; ++j) {
          float v = fmaxf(acc[i][j][r] + bcol[j], 0.f);
          int c = c0 + j * 16 + l15;
          outB[(size_t)row * 128 + c] = f2bf(v);
          if (EPI == 1) outF[(size_t)row * 128 + c] = v;
        }
      }
    }
  }
}

// ---------------- layer-3: width-64 mean agg + root + log_softmax ----------------
__global__ void k_agg3ls(const char* __restrict__ Y3, const char* __restrict__ R3,
                         const int* __restrict__ off, const int* __restrict__ col, int n,
                         float* __restrict__ out) {
  int wid = (blockIdx.x * blockDim.x + threadIdx.x) >> 6;
  int lane = threadIdx.x & 63;
  if (wid >= n) return;
  int g = lane >> 3, q = lane & 7;
  unsigned qb = (unsigned)q << 4;
  int s = off[wid], e = off[wid + 1];
  float acc[8];
#pragma unroll
  for (int t = 0; t < 8; ++t) acc[t] = 0.f;
  int e1 = e - 1;
  for (int j = s; j < e; j += 16) {
    int i0 = j + g, i1 = i0 + 8;
    int c0 = NTL(&col[min(i0, e1)]);
    int c1 = NTL(&col[min(i1, e1)]);
    float s0 = (i0 < e) ? 1.f : 0.f;
    float s1 = (i1 < e) ? 1.f : 0.f;
    uint4 u0 = *(const uint4*)(Y3 + (((unsigned)c0 << 7) + qb));
    uint4 u1 = *(const uint4*)(Y3 + (((unsigned)c1 << 7) + qb));
    ACC8(u0, s0);
    ACC8(u1, s1);
  }
#pragma unroll
  for (int t = 0; t < 8; ++t) {
    acc[t] += __shfl_xor(acc[t], 8);
    acc[t] += __shfl_xor(acc[t], 16);
    acc[t] += __shfl_xor(acc[t], 32);
  }
  float inv = 1.0f / fmaxf((float)(e - s), 1.0f);
  uint4 ur = *(const uint4*)(R3 + (((unsigned)wid << 7) + qb));
  float v[8];
  v[0] = acc[0] * inv + bflo(ur.x);
  v[1] = acc[1] * inv + bfhi(ur.x);
  v[2] = acc[2] * inv + bflo(ur.y);
  v[3] = acc[3] * inv + bfhi(ur.y);
  v[4] = acc[4] * inv + bflo(ur.z);
  v[5] = acc[5] * inv + bfhi(ur.z);
  v[6] = acc[6] * inv + bflo(ur.w);
  v[7] = acc[7] * inv + bfhi(ur.w);
  bool valid = q < 5;  // cols q*8..q*8+7 < 40
  float m = -INFINITY;
  if (valid) {
#pragma unroll
    for (int t = 0; t < 8; ++t) m = fmaxf(m, v[t]);
  }
  m = fmaxf(m, __shfl_xor(m, 1));
  m = fmaxf(m, __shfl_xor(m, 2));
  m = fmaxf(m, __shfl_xor(m, 4));
  float sum = 0.f;
  if (valid) {
#pragma unroll
    for (int t = 0; t < 8; ++t) sum += expf(v[t] - m);
  }
  sum += __shfl_xor(sum, 1);
  sum += __shfl_xor(sum, 2);
  sum += __shfl_xor(sum, 4);
  float ls = logf(sum);
  if (lane < 5) {
    float4 o0 = make_float4(v[0] - m - ls, v[1] - m - ls, v[2] - m - ls, v[3] - m - ls);
    float4 o1 = make_float4(v[4] - m - ls, v[5] - m - ls, v[6] - m - ls, v[7] - m - ls);
    float* op = out + (size_t)wid * NCLASS + lane * 8;
    *(float4*)op = o0;
    *(float4*)(op + 4) = o1;
  }
}

extern "C" void kernel_launch(void* const* d_in, const int* in_sizes, int n_in,
                              void* d_out, int out_size, void* d_ws, size_t ws_size,
                              hipStream_t stream) {
  const float* x = (const float*)d_in[0];
  const int* ei = (const int*)d_in[1];
  const float* W1l = (const float*)d_in[2];
  const float* b1 = (const float*)d_in[3];
  const float* W1r = (const float*)d_in[4];
  const float* W2l = (const float*)d_in[5];
  const float* b2 = (const float*)d_in[6];
  const float* W2r = (const float*)d_in[7];
  const float* W3l = (const float*)d_in[8];
  const float* b3 = (const float*)d_in[9];
  const float* W3r = (const float*)d_in[10];

  int N = in_sizes[0] / 128;
  int E = in_sizes[1] / 2;
  const int* src = ei;
  const int* dst = ei + E;
  int PART = (N + 7) / 8;
  int nbB = (E + BEDG - 1) / BEDG;

  char* wptr = (char*)d_ws;
  auto alloc = [&](size_t bytes) {
    void* p = (void*)wptr;
    wptr += (bytes + 255) & ~(size_t)255;
    return p;
  };
  int* off = (int*)alloc((size_t)(N + 1) * 4);
  int* cursor = (int*)alloc((size_t)N * 4);
  int* col = (int*)alloc((size_t)E * 4);
  int* bsum = (int*)alloc(256 * 4);
  int* boff = (int*)alloc(256 * 4);
  int* bcnt = (int*)alloc((size_t)nbB * 8 * 4);
  int* btot = (int*)alloc(16 * 4);
  int* bbase = (int*)alloc(16 * 4);
  unsigned short* Wth1 = (unsigned short*)alloc(32768 * 2);
  unsigned short* Wth2 = (unsigned short*)alloc(32768 * 2);
  unsigned short* Wth3 = (unsigned short*)alloc(16384 * 2);
  unsigned short* xb = (unsigned short*)alloc((size_t)N * 128 * 2);
  unsigned short* mb = (unsigned short*)alloc((size_t)N * 128 * 2);
  unsigned short* h1 = (unsigned short*)alloc((size_t)N * 128 * 2);
  unsigned short* h2 = (unsigned short*)alloc((size_t)N * 128 * 2);

  float* outLS = (float*)d_out;                     // [N][40]
  float* emb = (float*)d_out + (size_t)N * NCLASS;  // [N][128]

  // Aliases (lifetimes disjoint on the stream):
  int* ebuf = (int*)h2;      // E ints; dead before gemm2 writes h2
  unsigned short* Y3 = mb;   // bf16 [N][64]; mb dead after gemm2
  unsigned short* R3b = h1;  // bf16 [N][64]; h1 dead after gemm2

  // CSR build
  k_bcount<<<nbB, 256, 0, stream>>>(dst, E, PART, bcnt);
  k_bscanA<<<8, 256, 0, stream>>>(bcnt, nbB, btot);
  k_bbase<<<1, 64, 0, stream>>>(btot, bbase);
  k_place<<<nbB, 256, 0, stream>>>(dst, src, E, PART, bcnt, bbase, ebuf);
  hipMemsetAsync(cursor, 0, (size_t)N * 4, stream);
  k_hist2<<<2048, 256, 0, stream>>>(ebuf, bbase, PART, cursor);
  int nb = (N + 1023) / 1024;
  k_scan1<<<nb, 256, 0, stream>>>(cursor, off, bsum, N);
  k_scan2<<<1, 128, 0, stream>>>(bsum, boff, nb);
  k_scan3<<<(N + 255) / 256, 256, 0, stream>>>(off, boff, cursor, N, E);
  k_fill2<<<2048, 256, 0, stream>>>(ebuf, bbase, PART, cursor, col);

  int n8 = N * 16;
  k_cast<<<(n8 + 255) / 256, 256, 0, stream>>>((const float4*)x, (uint4*)xb, n8);
  k_prepw<<<(81920 + 255) / 256, 256, 0, stream>>>(W1l, W1r, W2l, W2r, W3l, W3r, Wth1,
                                                   Wth2, Wth3);

  int ab = (N * 64 + 255) / 256;
  int gb = (N + 127) / 128;

  // layer 1 (root == gather source == xb)
  k_aggb<<<ab, 256, 0, stream>>>((const char*)xb, off, col, N, (uint4*)mb);
  k_gemm_mfma<128, 2, 0><<<gb, 256, 0, stream>>>(mb, xb, Wth1, b1, N, nullptr, h1);
  // layer 2 (emb f32 + h2 bf16)
  k_aggb<<<ab, 256, 0, stream>>>((const char*)h1, off, col, N, (uint4*)mb);
  k_gemm_mfma<128, 2, 1><<<gb, 256, 0, stream>>>(mb, h1, Wth2, b2, N, emb, h2);
  // layer 3: project first (Y3 = h2@W3l, R3 = h2@W3r + b3, both bf16), then
  // width-64 aggregation with fused root add + log_softmax
  k_gemm_mfma<128, 1, 3><<<gb, 256, 0, stream>>>(h2, nullptr, Wth3, b3, N, (float*)R3b, Y3);
  k_agg3ls<<<ab, 256, 0, stream>>>((const char*)Y3, (const char*)R3b, off, col, N, outLS);
}

// Round 7
// 313.919 us; speedup vs baseline: 1.3520x; 1.3520x over previous
//
#include <hip/hip_runtime.h>
#include <math.h>

#define NCLASS 40
#define BEDG 1024
#define CAP 24576  // LDS col-staging capacity per 512-node sub-bucket

typedef float f32x4 __attribute__((ext_vector_type(4)));
typedef __bf16 bf16x8 __attribute__((ext_vector_type(8)));

typedef __attribute__((address_space(1))) const void gv_t;
typedef __attribute__((address_space(3))) void lv_t;
#define GLOAD_LDS16(g, l) __builtin_amdgcn_global_load_lds((gv_t*)(g), (lv_t*)(l), 16, 0, 0)
#define NTL(p) __builtin_nontemporal_load(p)

__device__ inline unsigned short f2bf(float f) {
  unsigned u = __float_as_uint(f);
  unsigned r = (u + 0x7fff + ((u >> 16) & 1)) >> 16;
  return (unsigned short)r;
}
__device__ inline float bflo(unsigned v) { return __uint_as_float(v << 16); }
__device__ inline float bfhi(unsigned v) { return __uint_as_float(v & 0xffff0000u); }

// ================= CSR build: two-level atomic-free counting sort =============
// Level 1: 8 coarse buckets (XCD node partitions). Level 2: 32 sub-buckets of
// 512 nodes each within a coarse bucket. Final per-sub-bucket CSR slice built
// in LDS, col streamed out coalesced (1x write, no global atomics).

// L1 pass a: per-1024-edge-block coarse counts
__global__ void k_bcount(const int* __restrict__ dst, int E, int PART,
                         int* __restrict__ bcnt) {
  __shared__ int lc[8];
  int k = blockIdx.x;
  if (threadIdx.x < 8) lc[threadIdx.x] = 0;
  __syncthreads();
  int lo = k * BEDG, hi = min(lo + BEDG, E);
  for (int i = lo + threadIdx.x; i < hi; i += blockDim.x)
    atomicAdd(&lc[NTL(&dst[i]) / PART], 1);
  __syncthreads();
  if (threadIdx.x < 8) bcnt[k * 8 + threadIdx.x] = lc[threadIdx.x];
}

// L1 pass b: per-bucket exclusive scan over blocks (one block per bucket)
__global__ void k_bscanA(int* __restrict__ bcnt, int nbB, int* __restrict__ btot) {
  __shared__ int tmp[256];
  __shared__ int carryS;
  int b = blockIdx.x;
  int tid = threadIdx.x;
  if (tid == 0) carryS = 0;
  __syncthreads();
  for (int c0 = 0; c0 < nbB; c0 += 256) {
    int idx = c0 + tid;
    int v = (idx < nbB) ? bcnt[idx * 8 + b] : 0;
    tmp[tid] = v;
    __syncthreads();
    for (int d = 1; d < 256; d <<= 1) {
      int t = (tid >= d) ? tmp[tid - d] : 0;
      __syncthreads();
      tmp[tid] += t;
      __syncthreads();
    }
    if (idx < nbB) bcnt[idx * 8 + b] = carryS + tmp[tid] - v;
    __syncthreads();
    if (tid == 255) carryS += tmp[255];
    __syncthreads();
  }
  if (tid == 0) btot[b] = carryS;
}

__global__ void k_bbase(const int* __restrict__ btot, int* __restrict__ bbase) {
  if (threadIdx.x == 0) {
    int s = 0;
    for (int b = 0; b < 8; ++b) {
      bbase[b] = s;
      s += btot[b];
    }
    bbase[8] = s;
  }
}

// L1 pass c: place packed (dstLocal<<17 | src) records, coarse-bucket-contiguous
__global__ void k_place(const int* __restrict__ dst, const int* __restrict__ src, int E,
                        int PART, const int* __restrict__ bcnt,
                        const int* __restrict__ bbase, int* __restrict__ ebuf) {
  __shared__ int lbase[8];
  __shared__ int lcnt[8];
  int k = blockIdx.x;
  if (threadIdx.x < 8) {
    lbase[threadIdx.x] = bbase[threadIdx.x] + bcnt[k * 8 + threadIdx.x];
    lcnt[threadIdx.x] = 0;
  }
  __syncthreads();
  int lo = k * BEDG, hi = min(lo + BEDG, E);
  for (int i = lo + threadIdx.x; i < hi; i += blockDim.x) {
    int d = NTL(&dst[i]);
    int s = NTL(&src[i]);
    int p = d / PART;
    int r = atomicAdd(&lcnt[p], 1);
    ebuf[lbase[p] + r] = (int)(((unsigned)(d - p * PART) << 17) | (unsigned)s);
  }
}

// L2 pass a: per (coarse p, chunk j) sub-bucket counts. p = blockIdx&7 (XCD-local)
__global__ void k_bcount2(const int* __restrict__ ebuf, const int* __restrict__ bbase,
                          int CB, int* __restrict__ bcnt2) {
  __shared__ int lc[32];
  int p = blockIdx.x & 7, j = blockIdx.x >> 3;
  int tid = threadIdx.x;
  if (tid < 32) lc[tid] = 0;
  __syncthreads();
  int lo = bbase[p], hi = bbase[p + 1];
  for (int base = lo + j * BEDG; base < hi; base += CB * BEDG) {
    int end = min(base + BEDG, hi);
    for (int i = base + tid; i < end; i += 256)
      atomicAdd(&lc[(((unsigned)NTL(&ebuf[i])) >> 17) >> 9], 1);
  }
  __syncthreads();
  if (tid < 32) bcnt2[(p * CB + j) * 32 + tid] = lc[tid];
}

// L2 pass b: per (p,k) exclusive scan over the CB chunk counts (CB <= 256)
__global__ void k_bscan2(int* __restrict__ bcnt2, int CB, int* __restrict__ tot2) {
  __shared__ int tmp[256];
  int p = blockIdx.x >> 5, k = blockIdx.x & 31;
  int tid = threadIdx.x;
  int v = (tid < CB) ? bcnt2[(p * CB + tid) * 32 + k] : 0;
  tmp[tid] = v;
  __syncthreads();
  for (int d = 1; d < 256; d <<= 1) {
    int t = (tid >= d) ? tmp[tid - d] : 0;
    __syncthreads();
    tmp[tid] += t;
    __syncthreads();
  }
  if (tid < CB) bcnt2[(p * CB + tid) * 32 + k] = tmp[tid] - v;
  if (tid == 255) tot2[p * 32 + k] = tmp[255];
}

// L2 pass c: sub-bucket global bases
__global__ void k_base2(const int* __restrict__ bbase, const int* __restrict__ tot2,
                        int* __restrict__ base2) {
  int p = threadIdx.x;
  if (p >= 8) return;
  int s = bbase[p];
  for (int k = 0; k < 32; ++k) {
    base2[p * 32 + k] = s;
    s += tot2[p * 32 + k];
  }
}

// L2 pass d: place into ebuf2, sub-bucket-contiguous
__global__ void k_place2(const int* __restrict__ ebuf, const int* __restrict__ bbase,
                         const int* __restrict__ bcnt2, const int* __restrict__ base2,
                         int CB, int* __restrict__ ebuf2) {
  __shared__ int lb[32];
  int p = blockIdx.x & 7, j = blockIdx.x >> 3;
  int tid = threadIdx.x;
  if (tid < 32) lb[tid] = base2[p * 32 + tid] + bcnt2[(p * CB + j) * 32 + tid];
  __syncthreads();
  int lo = bbase[p], hi = bbase[p + 1];
  for (int base = lo + j * BEDG; base < hi; base += CB * BEDG) {
    int end = min(base + BEDG, hi);
    for (int i = base + tid; i < end; i += 256) {
      unsigned pk = (unsigned)NTL(&ebuf[i]);
      int pos = atomicAdd(&lb[(pk >> 17) >> 9], 1);
      ebuf2[pos] = (int)pk;
    }
  }
}

// Final: one block per sub-bucket (<=512 nodes, contiguous edge range).
// Builds off[] + col[] slice entirely in LDS; col streamed out coalesced.
__global__ __launch_bounds__(256) void k_csr(const int* __restrict__ ebuf2,
                                             const int* __restrict__ base2,
                                             const int* __restrict__ tot2, int PART,
                                             int N, int E, int* __restrict__ off,
                                             int* __restrict__ col) {
  __shared__ int cnt[512];
  __shared__ int cur[512];
  __shared__ int tmp[256];
  __shared__ int stage[CAP];
  int p = blockIdx.x & 7, k = blockIdx.x >> 3;
  int tid = threadIdx.x;
  if (p == 0 && k == 0 && tid == 0) off[N] = E;
  int n0l = k << 9;
  if (n0l >= PART) return;
  int node0 = p * PART + n0l;
  if (node0 >= N) return;
  int nn = min(512, PART - n0l);
  nn = min(nn, N - node0);
  int lo = base2[p * 32 + k];
  int tot = tot2[p * 32 + k];

  cnt[tid] = 0;
  cnt[tid + 256] = 0;
  __syncthreads();
  for (int i = lo + tid; i < lo + tot; i += 256)
    atomicAdd(&cnt[(((unsigned)ebuf2[i]) >> 17) & 511], 1);
  __syncthreads();

  // exclusive scan of 512 counts (2 per thread)
  int v0 = cnt[2 * tid], v1 = cnt[2 * tid + 1];
  int s = v0 + v1;
  tmp[tid] = s;
  __syncthreads();
  for (int d = 1; d < 256; d <<= 1) {
    int t = (tid >= d) ? tmp[tid - d] : 0;
    __syncthreads();
    tmp[tid] += t;
    __syncthreads();
  }
  int excl = tmp[tid] - s;
  cnt[2 * tid] = excl;
  cnt[2 * tid + 1] = excl + v0;
  cur[2 * tid] = excl;
  cur[2 * tid + 1] = excl + v0;
  __syncthreads();

  for (int i = tid; i < nn; i += 256) off[node0 + i] = lo + cnt[i];

  if (tot <= CAP) {
    for (int i = lo + tid; i < lo + tot; i += 256) {
      unsigned pk = (unsigned)ebuf2[i];
      int pos = atomicAdd(&cur[(pk >> 17) & 511], 1);
      stage[pos] = (int)(pk & 0x1FFFFu);
    }
    __syncthreads();
    for (int i = tid; i < tot; i += 256) col[lo + i] = stage[i];
  } else {  // overflow fallback (never expected at this scale)
    for (int i = lo + tid; i < lo + tot; i += 256) {
      unsigned pk = (unsigned)ebuf2[i];
      int pos = atomicAdd(&cur[(pk >> 17) & 511], 1);
      col[lo + pos] = (int)(pk & 0x1FFFFu);
    }
  }
}

// ---------------- casts / weight prep ----------------
__global__ void k_cast(const float4* __restrict__ x, uint4* __restrict__ xb, int n8) {
  int i = blockIdx.x * blockDim.x + threadIdx.x;
  if (i >= n8) return;
  float4 a = x[i * 2], b = x[i * 2 + 1];
  uint4 o;
  o.x = (unsigned)f2bf(a.x) | ((unsigned)f2bf(a.y) << 16);
  o.y = (unsigned)f2bf(a.z) | ((unsigned)f2bf(a.w) << 16);
  o.z = (unsigned)f2bf(b.x) | ((unsigned)f2bf(b.y) << 16);
  o.w = (unsigned)f2bf(b.z) | ((unsigned)f2bf(b.w) << 16);
  xb[i] = o;
}

// Wth layout: [half][COLS][128] bf16. half0=Wl^T, half1=Wr^T.
__global__ void k_prepw(const float* __restrict__ W1l, const float* __restrict__ W1r,
                        const float* __restrict__ W2l, const float* __restrict__ W2r,
                        const float* __restrict__ W3l, const float* __restrict__ W3r,
                        unsigned short* __restrict__ Wth1, unsigned short* __restrict__ Wth2,
                        unsigned short* __restrict__ Wth3) {
  int idx = blockIdx.x * blockDim.x + threadIdx.x;
  if (idx < 32768) {
    int h = idx >> 14, c = (idx >> 7) & 127, k = idx & 127;
    const float* W = h ? W1r : W1l;
    Wth1[idx] = f2bf(W[k * 128 + c]);
  } else if (idx < 65536) {
    int j = idx - 32768;
    int h = j >> 14, c = (j >> 7) & 127, k = j & 127;
    const float* W = h ? W2r : W2l;
    Wth2[j] = f2bf(W[k * 128 + c]);
  } else if (idx < 65536 + 16384) {
    int j = idx - 65536;
    int h = j >> 13, c = (j >> 7) & 63, k = j & 127;
    float v = 0.f;
    if (c < NCLASS) v = (h ? W3r : W3l)[k * NCLASS + c];
    Wth3[j] = f2bf(v);
  }
}

// ---------------- mean aggregation, width 128, uint4 gathers ----------------
#define ACC8(u, sc)                          \
  acc[0] = fmaf(bflo(u.x), sc, acc[0]);      \
  acc[1] = fmaf(bfhi(u.x), sc, acc[1]);      \
  acc[2] = fmaf(bflo(u.y), sc, acc[2]);      \
  acc[3] = fmaf(bfhi(u.y), sc, acc[3]);      \
  acc[4] = fmaf(bflo(u.z), sc, acc[4]);      \
  acc[5] = fmaf(bfhi(u.z), sc, acc[5]);      \
  acc[6] = fmaf(bflo(u.w), sc, acc[6]);      \
  acc[7] = fmaf(bfhi(u.w), sc, acc[7]);

__global__ void k_aggb(const char* __restrict__ X, const int* __restrict__ off,
                       const int* __restrict__ col, int n, uint4* __restrict__ out) {
  int wid = (blockIdx.x * blockDim.x + threadIdx.x) >> 6;
  int lane = threadIdx.x & 63;
  if (wid >= n) return;
  int g = lane >> 4, q = lane & 15;
  unsigned qb = (unsigned)q << 4;
  int s = off[wid], e = off[wid + 1];
  float acc[8];
#pragma unroll
  for (int t = 0; t < 8; ++t) acc[t] = 0.f;
  int e1 = e - 1;
  for (int j = s; j < e; j += 8) {
    int i0 = j + g, i1 = i0 + 4;
    int c0 = NTL(&col[min(i0, e1)]);
    int c1 = NTL(&col[min(i1, e1)]);
    float s0 = (i0 < e) ? 1.f : 0.f;
    float s1 = (i1 < e) ? 1.f : 0.f;
    uint4 u0 = *(const uint4*)(X + (((unsigned)c0 << 8) + qb));
    uint4 u1 = *(const uint4*)(X + (((unsigned)c1 << 8) + qb));
    ACC8(u0, s0);
    ACC8(u1, s1);
  }
#pragma unroll
  for (int t = 0; t < 8; ++t) {
    acc[t] += __shfl_xor(acc[t], 16);
    acc[t] += __shfl_xor(acc[t], 32);
  }
  float inv = 1.0f / fmaxf((float)(e - s), 1.0f);
  uint4 o;
  o.x = (unsigned)f2bf(acc[0] * inv) | ((unsigned)f2bf(acc[1] * inv) << 16);
  o.y = (unsigned)f2bf(acc[2] * inv) | ((unsigned)f2bf(acc[3] * inv) << 16);
  o.z = (unsigned)f2bf(acc[4] * inv) | ((unsigned)f2bf(acc[5] * inv) << 16);
  o.w = (unsigned)f2bf(acc[6] * inv) | ((unsigned)f2bf(acc[7] * inv) << 16);
  if (lane < 16) out[(size_t)wid * 16 + lane] = o;
}

// ---------------- MFMA GEMM ----------------
template <int COLS, int HALVES, int EPI>
__global__ __launch_bounds__(256) void k_gemm_mfma(
    const unsigned short* __restrict__ Aagg, const unsigned short* __restrict__ Aroot,
    const unsigned short* __restrict__ Wth, const float* __restrict__ bias, int n,
    float* __restrict__ outF, unsigned short* __restrict__ outB) {
  constexpr int RF = 4;
  constexpr int CF = 4;
  __shared__ unsigned short aS[128 * 128];
  __shared__ unsigned short wS[COLS * 128];
  int tid = threadIdx.x;
  int w = tid >> 6, lane = tid & 63, l15 = lane & 15, kg = lane >> 4;
  int rowBase = blockIdx.x * 128;
  int r0 = (w >> 1) * 64;
  int c0 = (w & 1) * 64;

  f32x4 acc[RF][CF];
#pragma unroll
  for (int i = 0; i < RF; ++i)
#pragma unroll
    for (int j = 0; j < CF; ++j) acc[i][j] = (f32x4){0.f, 0.f, 0.f, 0.f};

#pragma unroll
  for (int half = 0; half < HALVES; ++half) {
    if (half) __syncthreads();
    {
      const unsigned short* As = half ? Aroot : Aagg;
#pragma unroll
      for (int it = 0; it < 8; ++it) {
        int row = it * 16 + (tid >> 4);
        int g = rowBase + row;
        g = (g < n) ? g : (n - 1);
        int cb = (tid & 15) << 4;
        int sb = cb ^ ((row & 7) << 4);
        const char* src = (const char*)(As + (size_t)g * 128) + sb;
        char* dst = (char*)aS + it * 4096 + (tid >> 6) * 1024;
        GLOAD_LDS16(src, dst);
      }
      const unsigned short* Ws = Wth + (size_t)half * COLS * 128;
#pragma unroll
      for (int it = 0; it < COLS / 16; ++it) {
        int c = it * 16 + (tid >> 4);
        int cb = (tid & 15) << 4;
        int sb = cb ^ ((c & 7) << 4);
        const char* src = (const char*)(Ws + (size_t)c * 128) + sb;
        char* dst = (char*)wS + it * 4096 + (tid >> 6) * 1024;
        GLOAD_LDS16(src, dst);
      }
      asm volatile("s_waitcnt vmcnt(0)" ::: "memory");
      __syncthreads();
    }
#pragma unroll
    for (int ks = 0; ks < 4; ++ks) {
      int kb = ks * 64 + kg * 16;
      bf16x8 av[RF], bv[CF];
#pragma unroll
      for (int i = 0; i < RF; ++i) {
        int row = r0 + i * 16 + l15;
        av[i] = *(const bf16x8*)((const char*)aS + row * 256 + (kb ^ ((row & 7) << 4)));
      }
#pragma unroll
      for (int j = 0; j < CF; ++j) {
        int c = c0 + j * 16 + l15;
        bv[j] = *(const bf16x8*)((const char*)wS + c * 256 + (kb ^ ((c & 7) << 4)));
      }
#pragma unroll
      for (int i = 0; i < RF; ++i)
#pragma unroll
        for (int j = 0; j < CF; ++j)
          acc[i][j] = __builtin_amdgcn_mfma_f32_16x16x32_bf16(av[i], bv[j], acc[i][j], 0, 0, 0);
    }
  }

  if (EPI == 3) {
    bool leftHalf = (c0 == 0);
    unsigned short* R3b = (unsigned short*)outF;
    float bcol[CF];
#pragma unroll
    for (int j = 0; j < CF; ++j) {
      int c = c0 + j * 16 + l15;
      bcol[j] = (!leftHalf && (c - 64) < NCLASS) ? bias[c - 64] : 0.f;
    }
#pragma unroll
    for (int i = 0; i < RF; ++i) {
#pragma unroll
      for (int r = 0; r < 4; ++r) {
        int row = rowBase + r0 + i * 16 + kg * 4 + r;
        if (row >= n) continue;
#pragma unroll
        for (int j = 0; j < CF; ++j) {
          int c = c0 + j * 16 + l15;
          if (leftHalf) {
            outB[(size_t)row * 64 + c] = f2bf(acc[i][j][r]);
          } else {
            R3b[(size_t)row * 64 + (c - 64)] = f2bf(acc[i][j][r] + bcol[j]);
          }
        }
      }
    }
  } else {
    float bcol[CF];
#pragma unroll
    for (int j = 0; j < CF; ++j) bcol[j] = bias[c0 + j * 16 + l15];
#pragma unroll
    for (int i = 0; i < RF; ++i) {
#pragma unroll
      for (int r = 0; r < 4; ++r) {
        int row = rowBase + r0 + i * 16 + kg * 4 + r;
        if (row >= n) continue;
#pragma unroll
        for (int j = 0; j < CF; ++j) {
          float v = fmaxf(acc[i][j][r] + bcol[j], 0.f);
          int c = c0 + j * 16 + l15;
          outB[(size_t)row * 128 + c] = f2bf(v);
          if (EPI == 1) outF[(size_t)row * 128 + c] = v;
        }
      }
    }
  }
}

// ---------------- layer-3: width-64 mean agg + root + log_softmax ----------------
__global__ void k_agg3ls(const char* __restrict__ Y3, const char* __restrict__ R3,
                         const int* __restrict__ off, const int* __restrict__ col, int n,
                         float* __restrict__ out) {
  int wid = (blockIdx.x * blockDim.x + threadIdx.x) >> 6;
  int lane = threadIdx.x & 63;
  if (wid >= n) return;
  int g = lane >> 3, q = lane & 7;
  unsigned qb = (unsigned)q << 4;
  int s = off[wid], e = off[wid + 1];
  float acc[8];
#pragma unroll
  for (int t = 0; t < 8; ++t) acc[t] = 0.f;
  int e1 = e - 1;
  for (int j = s; j < e; j += 16) {
    int i0 = j + g, i1 = i0 + 8;
    int c0 = NTL(&col[min(i0, e1)]);
    int c1 = NTL(&col[min(i1, e1)]);
    float s0 = (i0 < e) ? 1.f : 0.f;
    float s1 = (i1 < e) ? 1.f : 0.f;
    uint4 u0 = *(const uint4*)(Y3 + (((unsigned)c0 << 7) + qb));
    uint4 u1 = *(const uint4*)(Y3 + (((unsigned)c1 << 7) + qb));
    ACC8(u0, s0);
    ACC8(u1, s1);
  }
#pragma unroll
  for (int t = 0; t < 8; ++t) {
    acc[t] += __shfl_xor(acc[t], 8);
    acc[t] += __shfl_xor(acc[t], 16);
    acc[t] += __shfl_xor(acc[t], 32);
  }
  float inv = 1.0f / fmaxf((float)(e - s), 1.0f);
  uint4 ur = *(const uint4*)(R3 + (((unsigned)wid << 7) + qb));
  float v[8];
  v[0] = acc[0] * inv + bflo(ur.x);
  v[1] = acc[1] * inv + bfhi(ur.x);
  v[2] = acc[2] * inv + bflo(ur.y);
  v[3] = acc[3] * inv + bfhi(ur.y);
  v[4] = acc[4] * inv + bflo(ur.z);
  v[5] = acc[5] * inv + bfhi(ur.z);
  v[6] = acc[6] * inv + bflo(ur.w);
  v[7] = acc[7] * inv + bfhi(ur.w);
  bool valid = q < 5;  // cols q*8..q*8+7 < 40
  float m = -INFINITY;
  if (valid) {
#pragma unroll
    for (int t = 0; t < 8; ++t) m = fmaxf(m, v[t]);
  }
  m = fmaxf(m, __shfl_xor(m, 1));
  m = fmaxf(m, __shfl_xor(m, 2));
  m = fmaxf(m, __shfl_xor(m, 4));
  float sum = 0.f;
  if (valid) {
#pragma unroll
    for (int t = 0; t < 8; ++t) sum += expf(v[t] - m);
  }
  sum += __shfl_xor(sum, 1);
  sum += __shfl_xor(sum, 2);
  sum += __shfl_xor(sum, 4);
  float ls = logf(sum);
  if (lane < 5) {
    float4 o0 = make_float4(v[0] - m - ls, v[1] - m - ls, v[2] - m - ls, v[3] - m - ls);
    float4 o1 = make_float4(v[4] - m - ls, v[5] - m - ls, v[6] - m - ls, v[7] - m - ls);
    float* op = out + (size_t)wid * NCLASS + lane * 8;
    *(float4*)op = o0;
    *(float4*)(op + 4) = o1;
  }
}

extern "C" void kernel_launch(void* const* d_in, const int* in_sizes, int n_in,
                              void* d_out, int out_size, void* d_ws, size_t ws_size,
                              hipStream_t stream) {
  const float* x = (const float*)d_in[0];
  const int* ei = (const int*)d_in[1];
  const float* W1l = (const float*)d_in[2];
  const float* b1 = (const float*)d_in[3];
  const float* W1r = (const float*)d_in[4];
  const float* W2l = (const float*)d_in[5];
  const float* b2 = (const float*)d_in[6];
  const float* W2r = (const float*)d_in[7];
  const float* W3l = (const float*)d_in[8];
  const float* b3 = (const float*)d_in[9];
  const float* W3r = (const float*)d_in[10];

  int N = in_sizes[0] / 128;
  int E = in_sizes[1] / 2;
  const int* src = ei;
  const int* dst = ei + E;
  int PART = (N + 7) / 8;
  int nbB = (E + BEDG - 1) / BEDG;
  int CB = (E + 8 * BEDG - 1) / (8 * BEDG);
  if (CB > 256) CB = 256;
  if (CB < 1) CB = 1;

  char* wptr = (char*)d_ws;
  auto alloc = [&](size_t bytes) {
    void* p = (void*)wptr;
    wptr += (bytes + 255) & ~(size_t)255;
    return p;
  };
  int* off = (int*)alloc((size_t)(N + 1) * 4);
  int* col = (int*)alloc((size_t)E * 4);
  int* bcnt = (int*)alloc((size_t)nbB * 8 * 4);
  int* btot = (int*)alloc(16 * 4);
  int* bbase = (int*)alloc(16 * 4);
  int* bcnt2 = (int*)alloc((size_t)8 * CB * 32 * 4);
  int* tot2 = (int*)alloc(256 * 4);
  int* base2 = (int*)alloc(256 * 4);
  unsigned short* Wth1 = (unsigned short*)alloc(32768 * 2);
  unsigned short* Wth2 = (unsigned short*)alloc(32768 * 2);
  unsigned short* Wth3 = (unsigned short*)alloc(16384 * 2);
  unsigned short* xb = (unsigned short*)alloc((size_t)N * 128 * 2);
  unsigned short* mb = (unsigned short*)alloc((size_t)N * 128 * 2);
  unsigned short* h1 = (unsigned short*)alloc((size_t)N * 128 * 2);
  unsigned short* h2 = (unsigned short*)alloc((size_t)N * 128 * 2);

  float* outLS = (float*)d_out;                     // [N][40]
  float* emb = (float*)d_out + (size_t)N * NCLASS;  // [N][128]

  // Aliases (lifetimes disjoint on the stream): CSR build finishes before
  // any gemm writes h2; layer-3 reuses mb/h1 after gemm2.
  int* ebuf = (int*)h2;       // E ints
  int* ebuf2 = (int*)h2 + E;  // E ints (h2 region holds 2E ints: 12.8MB <= 25.6MB)
  unsigned short* Y3 = mb;    // bf16 [N][64]
  unsigned short* R3b = h1;   // bf16 [N][64]

  // CSR build: two-level counting sort, no global atomics
  k_bcount<<<nbB, 256, 0, stream>>>(dst, E, PART, bcnt);
  k_bscanA<<<8, 256, 0, stream>>>(bcnt, nbB, btot);
  k_bbase<<<1, 64, 0, stream>>>(btot, bbase);
  k_place<<<nbB, 256, 0, stream>>>(dst, src, E, PART, bcnt, bbase, ebuf);
  k_bcount2<<<8 * CB, 256, 0, stream>>>(ebuf, bbase, CB, bcnt2);
  k_bscan2<<<256, 256, 0, stream>>>(bcnt2, CB, tot2);
  k_base2<<<1, 64, 0, stream>>>(bbase, tot2, base2);
  k_place2<<<8 * CB, 256, 0, stream>>>(ebuf, bbase, bcnt2, base2, CB, ebuf2);
  k_csr<<<256, 256, 0, stream>>>(ebuf2, base2, tot2, PART, N, E, off, col);

  int n8 = N * 16;
  k_cast<<<(n8 + 255) / 256, 256, 0, stream>>>((const float4*)x, (uint4*)xb, n8);
  k_prepw<<<(81920 + 255) / 256, 256, 0, stream>>>(W1l, W1r, W2l, W2r, W3l, W3r, Wth1,
                                                   Wth2, Wth3);

  int ab = (N * 64 + 255) / 256;
  int gb = (N + 127) / 128;

  // layer 1 (root == gather source == xb)
  k_aggb<<<ab, 256, 0, stream>>>((const char*)xb, off, col, N, (uint4*)mb);
  k_gemm_mfma<128, 2, 0><<<gb, 256, 0, stream>>>(mb, xb, Wth1, b1, N, nullptr, h1);
  // layer 2 (emb f32 + h2 bf16)
  k_aggb<<<ab, 256, 0, stream>>>((const char*)h1, off, col, N, (uint4*)mb);
  k_gemm_mfma<128, 2, 1><<<gb, 256, 0, stream>>>(mb, h1, Wth2, b2, N, emb, h2);
  // layer 3: project first (Y3 = h2@W3l, R3 = h2@W3r + b3, both bf16), then
  // width-64 aggregation with fused root add + log_softmax
  k_gemm_mfma<128, 1, 3><<<gb, 256, 0, stream>>>(h2, nullptr, Wth3, b3, N, (float*)R3b, Y3);
  k_agg3ls<<<ab, 256, 0, stream>>>((const char*)Y3, (const char*)R3b, off, col, N, outLS);
}